// Round 3
// baseline (490.372 us; speedup 1.0000x reference)
//
#include <hip/hip_runtime.h>

#define LRELU(x) ((x) > 0.f ? (x) : 0.2f * (x))

typedef __attribute__((ext_vector_type(8))) short bf16x8;
typedef __attribute__((ext_vector_type(4))) float f32x4;

__device__ __forceinline__ unsigned short f2bf(float f) {
  unsigned int u = __float_as_uint(f);
  unsigned int r = (u + 0x7fffu + ((u >> 16) & 1u)) >> 16;  // RNE
  return (unsigned short)r;
}
__device__ __forceinline__ float bf2f(unsigned short u) {
  return __uint_as_float(((unsigned int)u) << 16);
}

// online softmax update / combine
__device__ __forceinline__ void oup(float e, float& m, float& s) {
  if (e <= m) s += __expf(e - m);
  else { s = s * __expf(m - e) + 1.f; m = e; }
}
__device__ __forceinline__ void ocomb(float om, float os, float& m, float& s) {
  float nm = fmaxf(m, om);
  s = s * __expf(m - nm) + os * __expf(om - nm);
  m = nm;
}

// ---- edge dtype detection ----
__global__ void detect_i64_kernel(const int* __restrict__ w, int* __restrict__ flag) {
  if (threadIdx.x == 0 && blockIdx.x == 0) {
    int all0 = 1;
    for (int j = 0; j < 128; j++)
      if (w[2 * j + 1] != 0) { all0 = 0; break; }
    *flag = all0;
  }
}
__device__ __forceinline__ int edge_at(const void* ei, long long idx, int is64) {
  if (is64) return (int)((const long long*)ei)[idx];
  return ((const int*)ei)[idx];
}

// ---- CSR build ----
__global__ void hist_kernel(const void* __restrict__ ei, const int* __restrict__ flag,
                            int* __restrict__ counts, int E, int N) {
  int i = blockIdx.x * blockDim.x + threadIdx.x;
  int tot = E + N;
  if (i >= tot) return;
  int f = *flag;
  int d = (i < E) ? edge_at(ei, (long long)E + i, f) : (i - E);
  atomicAdd(&counts[d], 1);
}

__global__ __launch_bounds__(512) void scan1_kernel(const int* __restrict__ counts,
                                                    int* __restrict__ partial,
                                                    int* __restrict__ blocksums, int N) {
  __shared__ int sm[1024];
  int t = threadIdx.x;
  int i = blockIdx.x * 512 + t;
  int v = (i < N) ? counts[i] : 0;
  int* cur = sm; int* nxt = sm + 512;
  cur[t] = v;
  __syncthreads();
  for (int off = 1; off < 512; off <<= 1) {
    int x = cur[t];
    if (t >= off) x += cur[t - off];
    nxt[t] = x;
    __syncthreads();
    int* tmp = cur; cur = nxt; nxt = tmp;
  }
  if (i < N) partial[i] = cur[t];
  if (t == 511) blocksums[blockIdx.x] = cur[511];
}

__global__ __launch_bounds__(512) void scan2_kernel(int* __restrict__ bs, int B) {
  __shared__ int sm[1024];
  int t = threadIdx.x;
  int v = (t < B) ? bs[t] : 0;
  int* cur = sm; int* nxt = sm + 512;
  cur[t] = v;
  __syncthreads();
  for (int off = 1; off < 512; off <<= 1) {
    int x = cur[t];
    if (t >= off) x += cur[t - off];
    nxt[t] = x;
    __syncthreads();
    int* tmp = cur; cur = nxt; nxt = tmp;
  }
  if (t < B) bs[t] = cur[t] - v;
}

__global__ void scan3_kernel(const int* __restrict__ partial, const int* __restrict__ bs,
                             int* __restrict__ row_ptr, int* __restrict__ cursor, int N) {
  int i = blockIdx.x * blockDim.x + threadIdx.x;
  if (i == 0) { row_ptr[0] = 0; cursor[0] = 0; }
  if (i < N) {
    int v = partial[i] + bs[i >> 9];
    row_ptr[i + 1] = v;
    if (i + 1 < N) cursor[i + 1] = v;
  }
}

__global__ void scatter_kernel(const void* __restrict__ ei, const int* __restrict__ flag,
                               int* __restrict__ cursor, int* __restrict__ srcs, int E, int N) {
  int i = blockIdx.x * blockDim.x + threadIdx.x;
  int tot = E + N;
  if (i >= tot) return;
  int f = *flag;
  int s, d;
  if (i < E) {
    s = edge_at(ei, i, f);
    d = edge_at(ei, (long long)E + i, f);
  } else {
    s = i - E; d = s;
  }
  int pos = atomicAdd(&cursor[d], 1);
  srcs[pos] = s;
}

// ---- prep: split fp32 -> bf16 hi/lo ----
__global__ __launch_bounds__(256) void split_kernel(const float* __restrict__ x,
                                                    unsigned short* __restrict__ xh,
                                                    unsigned short* __restrict__ xl, int n4) {
  int i = blockIdx.x * 256 + threadIdx.x;
  if (i >= n4) return;
  float4 v = ((const float4*)x)[i];
  ushort4 h, lo;
  h.x = f2bf(v.x); lo.x = f2bf(v.x - bf2f(h.x));
  h.y = f2bf(v.y); lo.y = f2bf(v.y - bf2f(h.y));
  h.z = f2bf(v.z); lo.z = f2bf(v.z - bf2f(h.z));
  h.w = f2bf(v.w); lo.w = f2bf(v.w - bf2f(h.w));
  ((ushort4*)xh)[i] = h;
  ((ushort4*)xl)[i] = lo;
}

// ---- prep: transpose + split W [K][Nc] -> Wt_h/Wt_l [Nc][K] ----
__global__ __launch_bounds__(256) void wprep_kernel(const float* __restrict__ W,
                                                    unsigned short* __restrict__ Wth,
                                                    unsigned short* __restrict__ Wtl,
                                                    int K, int Nc) {
  int idx = blockIdx.x * 256 + threadIdx.x;
  if (idx >= K * Nc) return;
  int n = idx / K, k = idx - n * K;
  float v = W[(size_t)k * Nc + n];
  unsigned short h = f2bf(v);
  Wth[idx] = h;
  Wtl[idx] = f2bf(v - bf2f(h));
}

// ---- MFMA GEMM (bf16 3-segment split = fp32-accurate), fused alpha epilogue ----
// C[M][BCOLS] = sum_seg A_seg[M][Ka] @ B_seg[BCOLS][Ka]^T  (B stored transposed [n][k])
// Writes bf16 Cb; fused: as[r*H+head] = sum_c h[r][c]*asrc[c] over this block's cols.
template <int BROWS, int BCOLS, int WALONG_N, int H>
__global__ __launch_bounds__(256) void gemm_mfma(
    const unsigned short* __restrict__ A0, const unsigned short* __restrict__ A1,
    const unsigned short* __restrict__ A2, const unsigned short* __restrict__ B0,
    const unsigned short* __restrict__ B1, const unsigned short* __restrict__ B2,
    int M, int Ka, unsigned short* __restrict__ Cb, const float* __restrict__ asrc,
    const float* __restrict__ adst, float* __restrict__ as, float* __restrict__ ad) {
  __shared__ __align__(16) unsigned short Asm[4][BROWS][8];
  __shared__ __align__(16) unsigned short Bsm[4][BCOLS][8];
  int tid = threadIdx.x;
  int w = tid >> 6, l = tid & 63;
  int l16 = l & 15, lg = l >> 4;
  int rowbase = blockIdx.y * BROWS;
  int wrow = WALONG_N ? 0 : w * 64;
  int wcol = WALONG_N ? w * 64 : 0;
  f32x4 acc[4][4] = {};
  const unsigned short* Aseg[3] = {A0, A1, A2};
  const unsigned short* Bseg[3] = {B0, B1, B2};
#pragma unroll
  for (int seg = 0; seg < 3; ++seg) {
    const unsigned short* Ap = Aseg[seg];
    const unsigned short* Bp = Bseg[seg];
    for (int k0 = 0; k0 < Ka; k0 += 32) {
      __syncthreads();
      for (int i = tid; i < BROWS * 4; i += 256) {
        int r = i >> 2, p = i & 3;
        bf16x8 v = {};
        int gr = rowbase + r;
        if (gr < M) v = *(const bf16x8*)(Ap + (size_t)gr * Ka + k0 + p * 8);
        *(bf16x8*)&Asm[p][r][0] = v;
      }
      for (int i = tid; i < BCOLS * 4; i += 256) {
        int r = i >> 2, p = i & 3;
        *(bf16x8*)&Bsm[p][r][0] = *(const bf16x8*)(Bp + (size_t)r * Ka + k0 + p * 8);
      }
      __syncthreads();
      bf16x8 af[4], bfr[4];
#pragma unroll
      for (int m = 0; m < 4; ++m) af[m] = *(const bf16x8*)&Asm[lg][wrow + m * 16 + l16][0];
#pragma unroll
      for (int n = 0; n < 4; ++n) bfr[n] = *(const bf16x8*)&Bsm[lg][wcol + n * 16 + l16][0];
#pragma unroll
      for (int m = 0; m < 4; ++m)
#pragma unroll
        for (int n = 0; n < 4; ++n)
          acc[m][n] = __builtin_amdgcn_mfma_f32_16x16x32_bf16(af[m], bfr[n], acc[m][n], 0, 0, 0);
    }
  }
  // epilogue: bf16 store
#pragma unroll
  for (int m = 0; m < 4; ++m) {
    int r = rowbase + wrow + m * 16 + lg * 4;
#pragma unroll
    for (int n = 0; n < 4; ++n) {
      int c = wcol + n * 16 + l16;
#pragma unroll
      for (int j = 0; j < 4; ++j) {
        if (r + j < M) Cb[(size_t)(r + j) * BCOLS + c] = f2bf(acc[m][n][j]);
      }
    }
  }
  // fused alpha: per-wave cols = one head (layer1) or whole row (layer2)
  float asv[4], adv_[4];
#pragma unroll
  for (int n = 0; n < 4; ++n) {
    int c = wcol + n * 16 + l16;
    asv[n] = asrc[c];
    adv_[n] = adst[c];
  }
  int head = WALONG_N ? w : 0;
#pragma unroll
  for (int m = 0; m < 4; ++m) {
#pragma unroll
    for (int j = 0; j < 4; ++j) {
      float ps = 0.f, pd = 0.f;
#pragma unroll
      for (int n = 0; n < 4; ++n) {
        ps = fmaf(acc[m][n][j], asv[n], ps);
        pd = fmaf(acc[m][n][j], adv_[n], pd);
      }
#pragma unroll
      for (int o = 1; o < 16; o <<= 1) { ps += __shfl_xor(ps, o); pd += __shfl_xor(pd, o); }
      int r = rowbase + wrow + m * 16 + lg * 4 + j;
      if (l16 == 0 && r < M) {
        as[(size_t)r * H + head] = ps;
        ad[(size_t)r * H + head] = pd;
      }
    }
  }
}

// ---- layer-1 aggregation: block per node, 4 waves; H=4, C=64 ----
__global__ __launch_bounds__(256) void agg4(const unsigned short* __restrict__ hb,
                                            const float* __restrict__ as,
                                            const float* __restrict__ ad,
                                            const int* __restrict__ row_ptr,
                                            const int* __restrict__ srcs,
                                            const float* __restrict__ bias,
                                            unsigned short* __restrict__ oh,
                                            unsigned short* __restrict__ ol, int N) {
  __shared__ __align__(16) float red[4][256];
  __shared__ float wm[4][4], wss[4][4];
  __shared__ float MS[8];
  int gw = blockIdx.x;
  int tid = threadIdx.x;
  int w = tid >> 6, l = tid & 63;
  int beg = row_ptr[gw], end = row_ptr[gw + 1];
  float4 adv = *(const float4*)(ad + (size_t)gw * 4);
  // phase 1: thread-strided online softmax
  float m0 = -1e30f, m1 = -1e30f, m2 = -1e30f, m3 = -1e30f;
  float s0 = 0.f, s1 = 0.f, s2 = 0.f, s3 = 0.f;
  for (int j = beg + tid; j < end; j += 256) {
    int sn = srcs[j];
    float4 a = *(const float4*)(as + (size_t)sn * 4);
    oup(LRELU(a.x + adv.x), m0, s0);
    oup(LRELU(a.y + adv.y), m1, s1);
    oup(LRELU(a.z + adv.z), m2, s2);
    oup(LRELU(a.w + adv.w), m3, s3);
  }
#pragma unroll
  for (int o = 32; o; o >>= 1) {
    float om, os;
    om = __shfl_xor(m0, o); os = __shfl_xor(s0, o); ocomb(om, os, m0, s0);
    om = __shfl_xor(m1, o); os = __shfl_xor(s1, o); ocomb(om, os, m1, s1);
    om = __shfl_xor(m2, o); os = __shfl_xor(s2, o); ocomb(om, os, m2, s2);
    om = __shfl_xor(m3, o); os = __shfl_xor(s3, o); ocomb(om, os, m3, s3);
  }
  if (l == 0) {
    wm[w][0] = m0; wss[w][0] = s0;
    wm[w][1] = m1; wss[w][1] = s1;
    wm[w][2] = m2; wss[w][2] = s2;
    wm[w][3] = m3; wss[w][3] = s3;
  }
  __syncthreads();
  if (tid < 4) {
    float M = -1e30f, S = 0.f;
    for (int i = 0; i < 4; i++) M = fmaxf(M, wm[i][tid]);
    for (int i = 0; i < 4; i++) S += wss[i][tid] * __expf(wm[i][tid] - M);
    MS[tid] = M;
    MS[4 + tid] = 1.f / (S + 1e-16f);
  }
  __syncthreads();
  // phase 2: wave-strided accumulate (lane owns 4 channels of head l>>4)
  int hh = l >> 4;
  float Mh = MS[hh], Ih = MS[4 + hh];
  float advh = hh == 0 ? adv.x : hh == 1 ? adv.y : hh == 2 ? adv.z : adv.w;
  float4 acc = make_float4(0.f, 0.f, 0.f, 0.f);
  for (int j = beg + w; j < end; j += 4) {
    int sn = srcs[j];
    float4 a = *(const float4*)(as + (size_t)sn * 4);
    float ah = hh == 0 ? a.x : hh == 1 ? a.y : hh == 2 ? a.z : a.w;
    float al = __expf(LRELU(ah + advh) - Mh) * Ih;
    ushort4 hv = *(const ushort4*)(hb + (size_t)sn * 256 + 4 * l);
    acc.x = fmaf(al, bf2f(hv.x), acc.x);
    acc.y = fmaf(al, bf2f(hv.y), acc.y);
    acc.z = fmaf(al, bf2f(hv.z), acc.z);
    acc.w = fmaf(al, bf2f(hv.w), acc.w);
  }
  *(float4*)&red[w][4 * l] = acc;
  __syncthreads();
  // phase 3: cross-wave reduce; thread = channel
  float v = red[0][tid] + red[1][tid] + red[2][tid] + red[3][tid];
  v = fmaxf(v + bias[tid], 0.f);
  unsigned short hi = f2bf(v);
  oh[(size_t)gw * 256 + tid] = hi;
  ol[(size_t)gw * 256 + tid] = f2bf(v - bf2f(hi));
}

// ---- layer-2 aggregation: block per node, 4 waves; H=1, C=64 ----
__global__ __launch_bounds__(256) void agg1(const unsigned short* __restrict__ hb,
                                            const float* __restrict__ as,
                                            const float* __restrict__ ad,
                                            const int* __restrict__ row_ptr,
                                            const int* __restrict__ srcs,
                                            const float* __restrict__ bias,
                                            float* __restrict__ out, int N) {
  __shared__ float red[4][64];
  __shared__ float wm[4], wss[4];
  __shared__ float MS[2];
  int gw = blockIdx.x;
  int tid = threadIdx.x;
  int w = tid >> 6, l = tid & 63;
  int beg = row_ptr[gw], end = row_ptr[gw + 1];
  float adn = ad[gw];
  float m = -1e30f, s = 0.f;
  for (int j = beg + tid; j < end; j += 256) {
    oup(LRELU(as[srcs[j]] + adn), m, s);
  }
#pragma unroll
  for (int o = 32; o; o >>= 1) {
    float om = __shfl_xor(m, o), os = __shfl_xor(s, o);
    ocomb(om, os, m, s);
  }
  if (l == 0) { wm[w] = m; wss[w] = s; }
  __syncthreads();
  if (tid == 0) {
    float M = -1e30f, S = 0.f;
    for (int i = 0; i < 4; i++) M = fmaxf(M, wm[i]);
    for (int i = 0; i < 4; i++) S += wss[i] * __expf(wm[i] - M);
    MS[0] = M;
    MS[1] = 1.f / (S + 1e-16f);
  }
  __syncthreads();
  float M = MS[0], inv = MS[1];
  float acc = 0.f;
  for (int j = beg + w; j < end; j += 4) {
    int sn = srcs[j];
    float al = __expf(LRELU(as[sn] + adn) - M) * inv;
    acc = fmaf(al, bf2f(hb[(size_t)sn * 64 + l]), acc);
  }
  red[w][l] = acc;
  __syncthreads();
  if (tid < 64) {
    float v = red[0][tid] + red[1][tid] + red[2][tid] + red[3][tid];
    out[(size_t)gw * 64 + tid] = v + bias[tid];
  }
}

extern "C" void kernel_launch(void* const* d_in, const int* in_sizes, int n_in,
                              void* d_out, int out_size, void* d_ws, size_t ws_size,
                              hipStream_t stream) {
  const float* x      = (const float*)d_in[0];
  const void*  ei     = d_in[1];
  const float* W1     = (const float*)d_in[2];
  const float* a_src1 = (const float*)d_in[3];
  const float* a_dst1 = (const float*)d_in[4];
  const float* b1     = (const float*)d_in[5];
  const float* W2     = (const float*)d_in[6];
  const float* a_src2 = (const float*)d_in[7];
  const float* a_dst2 = (const float*)d_in[8];
  const float* b2     = (const float*)d_in[9];

  const int Fin = 128;
  const int N   = in_sizes[0] / Fin;  // 50000
  const int E   = in_sizes[1] / 2;    // 800000
  const int HC1 = in_sizes[2] / Fin;  // 256
  const int Etot = E + N;

  char* wp = (char*)d_ws;
  auto alloc = [&](size_t bytes) {
    void* p = (void*)wp;
    wp += (bytes + 255) & ~(size_t)255;
    return p;
  };
  int* counts    = (int*)alloc((size_t)N * 4);
  int* row_ptr   = (int*)alloc((size_t)(N + 1) * 4);
  int* cursor    = (int*)alloc((size_t)N * 4);
  int* partial   = (int*)alloc((size_t)N * 4);
  int* blocksums = (int*)alloc(4096);
  int* flag      = (int*)alloc(256);
  int* srcs      = (int*)alloc((size_t)Etot * 4);
  unsigned short* xh   = (unsigned short*)alloc((size_t)N * Fin * 2);  // 12.8MB
  unsigned short* xl   = (unsigned short*)alloc((size_t)N * Fin * 2);  // contiguous after xh
  unsigned short* W1th = (unsigned short*)alloc((size_t)HC1 * Fin * 2);
  unsigned short* W1tl = (unsigned short*)alloc((size_t)HC1 * Fin * 2);
  unsigned short* W2th = (unsigned short*)alloc((size_t)64 * HC1 * 2);
  unsigned short* W2tl = (unsigned short*)alloc((size_t)64 * HC1 * 2);
  unsigned short* h1b  = (unsigned short*)alloc((size_t)N * 256 * 2);  // 25.6MB
  float* as1 = (float*)alloc((size_t)N * 4 * 4);
  float* ad1 = (float*)alloc((size_t)N * 4 * 4);
  unsigned short* o1l = (unsigned short*)alloc((size_t)N * 256 * 2);   // 25.6MB
  float* as2 = (float*)alloc((size_t)N * 4);
  float* ad2 = (float*)alloc((size_t)N * 4);
  // aliases (lifetimes are disjoint):
  unsigned short* o1h = xh;   // xh+xl contiguous 25.6MB, free after gemm1
  unsigned short* h2b = h1b;  // h1b free after agg4

  const int SB = (N + 511) / 512;

  // ---- CSR build ----
  detect_i64_kernel<<<1, 64, 0, stream>>>((const int*)ei, flag);
  hipMemsetAsync(counts, 0, (size_t)N * 4, stream);
  hist_kernel<<<(Etot + 255) / 256, 256, 0, stream>>>(ei, flag, counts, E, N);
  scan1_kernel<<<SB, 512, 0, stream>>>(counts, partial, blocksums, N);
  scan2_kernel<<<1, 512, 0, stream>>>(blocksums, SB);
  scan3_kernel<<<(N + 255) / 256, 256, 0, stream>>>(partial, blocksums, row_ptr, cursor, N);
  scatter_kernel<<<(Etot + 255) / 256, 256, 0, stream>>>(ei, flag, cursor, srcs, E, N);

  // ---- prep ----
  int n4 = N * Fin / 4;
  split_kernel<<<(n4 + 255) / 256, 256, 0, stream>>>(x, xh, xl, n4);
  wprep_kernel<<<(Fin * HC1 + 255) / 256, 256, 0, stream>>>(W1, W1th, W1tl, Fin, HC1);
  wprep_kernel<<<(HC1 * 64 + 255) / 256, 256, 0, stream>>>(W2, W2th, W2tl, HC1, 64);

  // ---- layer 1: GEMM (M=N, Ka=128, cols=256) + fused alpha ----
  gemm_mfma<64, 256, 1, 4><<<dim3(1, (N + 63) / 64), 256, 0, stream>>>(
      xh, xh, xl, W1th, W1tl, W1th, N, Fin, h1b, a_src1, a_dst1, as1, ad1);
  agg4<<<N, 256, 0, stream>>>(h1b, as1, ad1, row_ptr, srcs, b1, o1h, o1l, N);

  // ---- layer 2: GEMM (M=N, Ka=256, cols=64) + fused alpha ----
  gemm_mfma<256, 64, 0, 1><<<dim3(1, (N + 255) / 256), 256, 0, stream>>>(
      o1h, o1h, o1l, W2th, W2tl, W2th, N, HC1, h2b, a_src2, a_dst2, as2, ad2);
  agg1<<<N, 256, 0, stream>>>(h2b, as2, ad2, row_ptr, srcs, b2, (float*)d_out, N);
}

// Round 4
// 296.787 us; speedup vs baseline: 1.6523x; 1.6523x over previous
//
#include <hip/hip_runtime.h>

#define LRELU(x) ((x) > 0.f ? (x) : 0.2f * (x))

typedef __attribute__((ext_vector_type(8))) short bf16x8;
typedef __attribute__((ext_vector_type(4))) float f32x4;

__device__ __forceinline__ unsigned short f2bf(float f) {
  unsigned int u = __float_as_uint(f);
  unsigned int r = (u + 0x7fffu + ((u >> 16) & 1u)) >> 16;  // RNE
  return (unsigned short)r;
}
__device__ __forceinline__ float bf2f(unsigned short u) {
  return __uint_as_float(((unsigned int)u) << 16);
}
__device__ __forceinline__ float bflo(unsigned int u) { return __uint_as_float(u << 16); }
__device__ __forceinline__ float bfhi(unsigned int u) { return __uint_as_float(u & 0xffff0000u); }

// ---- edge dtype detection ----
__global__ void detect_i64_kernel(const int* __restrict__ w, int* __restrict__ flag) {
  if (threadIdx.x == 0 && blockIdx.x == 0) {
    int all0 = 1;
    for (int j = 0; j < 128; j++)
      if (w[2 * j + 1] != 0) { all0 = 0; break; }
    *flag = all0;
  }
}
__device__ __forceinline__ int edge_at(const void* ei, long long idx, int is64) {
  if (is64) return (int)((const long long*)ei)[idx];
  return ((const int*)ei)[idx];
}

// ---- CSR build ----
__global__ void hist_kernel(const void* __restrict__ ei, const int* __restrict__ flag,
                            int* __restrict__ counts, int E, int N) {
  int i = blockIdx.x * blockDim.x + threadIdx.x;
  int tot = E + N;
  if (i >= tot) return;
  int f = *flag;
  int d = (i < E) ? edge_at(ei, (long long)E + i, f) : (i - E);
  atomicAdd(&counts[d], 1);
}

__global__ __launch_bounds__(512) void scan1_kernel(const int* __restrict__ counts,
                                                    int* __restrict__ partial,
                                                    int* __restrict__ blocksums, int N) {
  __shared__ int sm[1024];
  int t = threadIdx.x;
  int i = blockIdx.x * 512 + t;
  int v = (i < N) ? counts[i] : 0;
  int* cur = sm; int* nxt = sm + 512;
  cur[t] = v;
  __syncthreads();
  for (int off = 1; off < 512; off <<= 1) {
    int x = cur[t];
    if (t >= off) x += cur[t - off];
    nxt[t] = x;
    __syncthreads();
    int* tmp = cur; cur = nxt; nxt = tmp;
  }
  if (i < N) partial[i] = cur[t];
  if (t == 511) blocksums[blockIdx.x] = cur[511];
}

__global__ __launch_bounds__(512) void scan2_kernel(int* __restrict__ bs, int B) {
  __shared__ int sm[1024];
  int t = threadIdx.x;
  int v = (t < B) ? bs[t] : 0;
  int* cur = sm; int* nxt = sm + 512;
  cur[t] = v;
  __syncthreads();
  for (int off = 1; off < 512; off <<= 1) {
    int x = cur[t];
    if (t >= off) x += cur[t - off];
    nxt[t] = x;
    __syncthreads();
    int* tmp = cur; cur = nxt; nxt = tmp;
  }
  if (t < B) bs[t] = cur[t] - v;
}

__global__ void scan3_kernel(const int* __restrict__ partial, const int* __restrict__ bs,
                             int* __restrict__ row_ptr, int* __restrict__ cursor, int N) {
  int i = blockIdx.x * blockDim.x + threadIdx.x;
  if (i == 0) { row_ptr[0] = 0; cursor[0] = 0; }
  if (i < N) {
    int v = partial[i] + bs[i >> 9];
    row_ptr[i + 1] = v;
    if (i + 1 < N) cursor[i + 1] = v;
  }
}

__global__ void scatter_kernel(const void* __restrict__ ei, const int* __restrict__ flag,
                               int* __restrict__ cursor, int* __restrict__ srcs, int E, int N) {
  int i = blockIdx.x * blockDim.x + threadIdx.x;
  int tot = E + N;
  if (i >= tot) return;
  int f = *flag;
  int s, d;
  if (i < E) {
    s = edge_at(ei, i, f);
    d = edge_at(ei, (long long)E + i, f);
  } else {
    s = i - E; d = s;
  }
  int pos = atomicAdd(&cursor[d], 1);
  srcs[pos] = s;
}

// ---- prep: split fp32 -> bf16 hi/lo ----
__global__ __launch_bounds__(256) void split_kernel(const float* __restrict__ x,
                                                    unsigned short* __restrict__ xh,
                                                    unsigned short* __restrict__ xl, int n4) {
  int i = blockIdx.x * 256 + threadIdx.x;
  if (i >= n4) return;
  float4 v = ((const float4*)x)[i];
  ushort4 h, lo;
  h.x = f2bf(v.x); lo.x = f2bf(v.x - bf2f(h.x));
  h.y = f2bf(v.y); lo.y = f2bf(v.y - bf2f(h.y));
  h.z = f2bf(v.z); lo.z = f2bf(v.z - bf2f(h.z));
  h.w = f2bf(v.w); lo.w = f2bf(v.w - bf2f(h.w));
  ((ushort4*)xh)[i] = h;
  ((ushort4*)xl)[i] = lo;
}

// ---- prep: transpose + split W [K][Nc] -> Wt_h/Wt_l [Nc][K] ----
__global__ __launch_bounds__(256) void wprep_kernel(const float* __restrict__ W,
                                                    unsigned short* __restrict__ Wth,
                                                    unsigned short* __restrict__ Wtl,
                                                    int K, int Nc) {
  int idx = blockIdx.x * 256 + threadIdx.x;
  if (idx >= K * Nc) return;
  int n = idx / K, k = idx - n * K;
  float v = W[(size_t)k * Nc + n];
  unsigned short h = f2bf(v);
  Wth[idx] = h;
  Wtl[idx] = f2bf(v - bf2f(h));
}

// ---- MFMA GEMM (bf16 split-segment), fused alpha epilogue ----
template <int BROWS, int BCOLS, int WALONG_N, int H, int NSEG>
__global__ __launch_bounds__(256) void gemm_mfma(
    const unsigned short* __restrict__ A0, const unsigned short* __restrict__ A1,
    const unsigned short* __restrict__ A2, const unsigned short* __restrict__ B0,
    const unsigned short* __restrict__ B1, const unsigned short* __restrict__ B2,
    int M, int Ka, unsigned short* __restrict__ Cb, const float* __restrict__ asrc,
    const float* __restrict__ adst, float* __restrict__ as, float* __restrict__ ad) {
  __shared__ __align__(16) unsigned short Asm[4][BROWS][8];
  __shared__ __align__(16) unsigned short Bsm[4][BCOLS][8];
  int tid = threadIdx.x;
  int w = tid >> 6, l = tid & 63;
  int l16 = l & 15, lg = l >> 4;
  int rowbase = blockIdx.y * BROWS;
  int wrow = WALONG_N ? 0 : w * 64;
  int wcol = WALONG_N ? w * 64 : 0;
  f32x4 acc[4][4] = {};
  const unsigned short* Aseg[3] = {A0, A1, A2};
  const unsigned short* Bseg[3] = {B0, B1, B2};
#pragma unroll
  for (int seg = 0; seg < NSEG; ++seg) {
    const unsigned short* Ap = Aseg[seg];
    const unsigned short* Bp = Bseg[seg];
    for (int k0 = 0; k0 < Ka; k0 += 32) {
      __syncthreads();
      for (int i = tid; i < BROWS * 4; i += 256) {
        int r = i >> 2, p = i & 3;
        bf16x8 v = {};
        int gr = rowbase + r;
        if (gr < M) v = *(const bf16x8*)(Ap + (size_t)gr * Ka + k0 + p * 8);
        *(bf16x8*)&Asm[p][r][0] = v;
      }
      for (int i = tid; i < BCOLS * 4; i += 256) {
        int r = i >> 2, p = i & 3;
        *(bf16x8*)&Bsm[p][r][0] = *(const bf16x8*)(Bp + (size_t)r * Ka + k0 + p * 8);
      }
      __syncthreads();
      bf16x8 af[4], bfr[4];
#pragma unroll
      for (int m = 0; m < 4; ++m) af[m] = *(const bf16x8*)&Asm[lg][wrow + m * 16 + l16][0];
#pragma unroll
      for (int n = 0; n < 4; ++n) bfr[n] = *(const bf16x8*)&Bsm[lg][wcol + n * 16 + l16][0];
#pragma unroll
      for (int m = 0; m < 4; ++m)
#pragma unroll
        for (int n = 0; n < 4; ++n)
          acc[m][n] = __builtin_amdgcn_mfma_f32_16x16x32_bf16(af[m], bfr[n], acc[m][n], 0, 0, 0);
    }
  }
#pragma unroll
  for (int m = 0; m < 4; ++m) {
    int r = rowbase + wrow + m * 16 + lg * 4;
#pragma unroll
    for (int n = 0; n < 4; ++n) {
      int c = wcol + n * 16 + l16;
#pragma unroll
      for (int j = 0; j < 4; ++j) {
        if (r + j < M) Cb[(size_t)(r + j) * BCOLS + c] = f2bf(acc[m][n][j]);
      }
    }
  }
  float asv[4], adv_[4];
#pragma unroll
  for (int n = 0; n < 4; ++n) {
    int c = wcol + n * 16 + l16;
    asv[n] = asrc[c];
    adv_[n] = adst[c];
  }
  int head = WALONG_N ? w : 0;
#pragma unroll
  for (int m = 0; m < 4; ++m) {
#pragma unroll
    for (int j = 0; j < 4; ++j) {
      float ps = 0.f, pd = 0.f;
#pragma unroll
      for (int n = 0; n < 4; ++n) {
        ps = fmaf(acc[m][n][j], asv[n], ps);
        pd = fmaf(acc[m][n][j], adv_[n], pd);
      }
#pragma unroll
      for (int o = 1; o < 16; o <<= 1) { ps += __shfl_xor(ps, o); pd += __shfl_xor(pd, o); }
      int r = rowbase + wrow + m * 16 + lg * 4 + j;
      if (l16 == 0 && r < M) {
        as[(size_t)r * H + head] = ps;
        ad[(size_t)r * H + head] = pd;
      }
    }
  }
}

// ---- layer-1 aggregation: wave per node; lane=(g,p): edge-offset g, 16 channels p ----
__global__ __launch_bounds__(256) void agg4(const unsigned short* __restrict__ hb,
                                            const float* __restrict__ as,
                                            const float* __restrict__ ad,
                                            const int* __restrict__ row_ptr,
                                            const int* __restrict__ srcs,
                                            const float* __restrict__ bias,
                                            unsigned short* __restrict__ oh, int N) {
  __shared__ float els[4][128][4];
  int tid = threadIdx.x;
  int w = tid >> 6, l = tid & 63;
  int gw = (blockIdx.x << 2) + w;
  if (gw >= N) gw = N - 1;  // benign duplicate (grid is exact when N%4==0)
  int g = l >> 4, p = l & 15;
  int beg = row_ptr[gw], end = row_ptr[gw + 1];
  float4 adv = *(const float4*)(ad + (size_t)gw * 4);
  // phase 1: per-lane max over strided edges; stash e in LDS
  float m0 = -1e30f, m1 = -1e30f, m2 = -1e30f, m3 = -1e30f;
  for (int j = beg + l; j < end; j += 64) {
    int sn = srcs[j];
    float4 a = *(const float4*)(as + (size_t)sn * 4);
    float e0 = LRELU(a.x + adv.x), e1 = LRELU(a.y + adv.y);
    float e2 = LRELU(a.z + adv.z), e3 = LRELU(a.w + adv.w);
    int slot = j - beg;
    if (slot < 128) {
      els[w][slot][0] = e0; els[w][slot][1] = e1;
      els[w][slot][2] = e2; els[w][slot][3] = e3;
    }
    m0 = fmaxf(m0, e0); m1 = fmaxf(m1, e1);
    m2 = fmaxf(m2, e2); m3 = fmaxf(m3, e3);
  }
#pragma unroll
  for (int o = 32; o; o >>= 1) {
    m0 = fmaxf(m0, __shfl_xor(m0, o));
    m1 = fmaxf(m1, __shfl_xor(m1, o));
    m2 = fmaxf(m2, __shfl_xor(m2, o));
    m3 = fmaxf(m3, __shfl_xor(m3, o));
  }
  __syncthreads();  // stash visible to all lanes (and all waves reach this)
  // phase 2: sum of exp over own slots
  float s0 = 0.f, s1 = 0.f, s2 = 0.f, s3 = 0.f;
  for (int j = beg + l; j < end; j += 64) {
    int slot = j - beg;
    float e0, e1, e2, e3;
    if (slot < 128) {
      e0 = els[w][slot][0]; e1 = els[w][slot][1];
      e2 = els[w][slot][2]; e3 = els[w][slot][3];
    } else {
      int sn = srcs[j];
      float4 a = *(const float4*)(as + (size_t)sn * 4);
      e0 = LRELU(a.x + adv.x); e1 = LRELU(a.y + adv.y);
      e2 = LRELU(a.z + adv.z); e3 = LRELU(a.w + adv.w);
    }
    s0 += __expf(e0 - m0); s1 += __expf(e1 - m1);
    s2 += __expf(e2 - m2); s3 += __expf(e3 - m3);
  }
#pragma unroll
  for (int o = 32; o; o >>= 1) {
    s0 += __shfl_xor(s0, o); s1 += __shfl_xor(s1, o);
    s2 += __shfl_xor(s2, o); s3 += __shfl_xor(s3, o);
  }
  float i0 = 1.f / (s0 + 1e-16f), i1 = 1.f / (s1 + 1e-16f);
  float i2 = 1.f / (s2 + 1e-16f), i3 = 1.f / (s3 + 1e-16f);
  // phase 3: accumulate. lane handles edge j0+g, channels p*16..p*16+15 (head=p>>2)
  int head = p >> 2;
  float Mh   = head == 0 ? m0 : head == 1 ? m1 : head == 2 ? m2 : m3;
  float Ih   = head == 0 ? i0 : head == 1 ? i1 : head == 2 ? i2 : i3;
  float advh = head == 0 ? adv.x : head == 1 ? adv.y : head == 2 ? adv.z : adv.w;
  float acc[16] = {};
  for (int j0 = beg; j0 < end; j0 += 4) {
    int j = j0 + g;
    if (j < end) {
      int sn = srcs[j];
      int slot = j - beg;
      float e;
      if (slot < 128) {
        e = els[w][slot][head];
      } else {
        float4 a = *(const float4*)(as + (size_t)sn * 4);
        float ah = head == 0 ? a.x : head == 1 ? a.y : head == 2 ? a.z : a.w;
        e = LRELU(ah + advh);
      }
      float al = __expf(e - Mh) * Ih;
      const unsigned short* hp = hb + (size_t)sn * 256 + p * 16;
      uint4 v0 = *(const uint4*)(hp);
      uint4 v1 = *(const uint4*)(hp + 8);
      acc[0]  = fmaf(al, bflo(v0.x), acc[0]);  acc[1]  = fmaf(al, bfhi(v0.x), acc[1]);
      acc[2]  = fmaf(al, bflo(v0.y), acc[2]);  acc[3]  = fmaf(al, bfhi(v0.y), acc[3]);
      acc[4]  = fmaf(al, bflo(v0.z), acc[4]);  acc[5]  = fmaf(al, bfhi(v0.z), acc[5]);
      acc[6]  = fmaf(al, bflo(v0.w), acc[6]);  acc[7]  = fmaf(al, bfhi(v0.w), acc[7]);
      acc[8]  = fmaf(al, bflo(v1.x), acc[8]);  acc[9]  = fmaf(al, bfhi(v1.x), acc[9]);
      acc[10] = fmaf(al, bflo(v1.y), acc[10]); acc[11] = fmaf(al, bfhi(v1.y), acc[11]);
      acc[12] = fmaf(al, bflo(v1.z), acc[12]); acc[13] = fmaf(al, bfhi(v1.z), acc[13]);
      acc[14] = fmaf(al, bflo(v1.w), acc[14]); acc[15] = fmaf(al, bfhi(v1.w), acc[15]);
    }
  }
  // combine the 4 edge-groups (lanes p, p+16, p+32, p+48)
#pragma unroll
  for (int i = 0; i < 16; ++i) acc[i] += __shfl_xor(acc[i], 16);
#pragma unroll
  for (int i = 0; i < 16; ++i) acc[i] += __shfl_xor(acc[i], 32);
  // lane writes channels p*16 + g*4 .. +3 (compile-time reg indices via selects)
  float o0 = g == 0 ? acc[0] : g == 1 ? acc[4]  : g == 2 ? acc[8]  : acc[12];
  float o1 = g == 0 ? acc[1] : g == 1 ? acc[5]  : g == 2 ? acc[9]  : acc[13];
  float o2 = g == 0 ? acc[2] : g == 1 ? acc[6]  : g == 2 ? acc[10] : acc[14];
  float o3 = g == 0 ? acc[3] : g == 1 ? acc[7]  : g == 2 ? acc[11] : acc[15];
  int c = p * 16 + g * 4;
  ushort4 ov;
  ov.x = f2bf(fmaxf(o0 + bias[c + 0], 0.f));
  ov.y = f2bf(fmaxf(o1 + bias[c + 1], 0.f));
  ov.z = f2bf(fmaxf(o2 + bias[c + 2], 0.f));
  ov.w = f2bf(fmaxf(o3 + bias[c + 3], 0.f));
  *(ushort4*)(oh + (size_t)gw * 256 + c) = ov;
}

// ---- layer-2 aggregation: wave per node; lane=(g,p): edge g, 4 channels p ----
__global__ __launch_bounds__(256) void agg1(const unsigned short* __restrict__ hb,
                                            const float* __restrict__ as,
                                            const float* __restrict__ ad,
                                            const int* __restrict__ row_ptr,
                                            const int* __restrict__ srcs,
                                            const float* __restrict__ bias,
                                            float* __restrict__ out, int N) {
  __shared__ float els[4][128];
  int tid = threadIdx.x;
  int w = tid >> 6, l = tid & 63;
  int gw = (blockIdx.x << 2) + w;
  if (gw >= N) gw = N - 1;
  int g = l >> 4, p = l & 15;
  int beg = row_ptr[gw], end = row_ptr[gw + 1];
  float adn = ad[gw];
  float m = -1e30f;
  for (int j = beg + l; j < end; j += 64) {
    float e = LRELU(as[srcs[j]] + adn);
    int slot = j - beg;
    if (slot < 128) els[w][slot] = e;
    m = fmaxf(m, e);
  }
#pragma unroll
  for (int o = 32; o; o >>= 1) m = fmaxf(m, __shfl_xor(m, o));
  __syncthreads();
  float s = 0.f;
  for (int j = beg + l; j < end; j += 64) {
    int slot = j - beg;
    float e = (slot < 128) ? els[w][slot] : LRELU(as[srcs[j]] + adn);
    s += __expf(e - m);
  }
#pragma unroll
  for (int o = 32; o; o >>= 1) s += __shfl_xor(s, o);
  float inv = 1.f / (s + 1e-16f);
  float acc[4] = {};
  for (int j0 = beg; j0 < end; j0 += 4) {
    int j = j0 + g;
    if (j < end) {
      int sn = srcs[j];
      int slot = j - beg;
      float e = (slot < 128) ? els[w][slot] : LRELU(as[sn] + adn);
      float al = __expf(e - m) * inv;
      ushort4 hv = *(const ushort4*)(hb + (size_t)sn * 64 + p * 4);
      acc[0] = fmaf(al, bf2f(hv.x), acc[0]);
      acc[1] = fmaf(al, bf2f(hv.y), acc[1]);
      acc[2] = fmaf(al, bf2f(hv.z), acc[2]);
      acc[3] = fmaf(al, bf2f(hv.w), acc[3]);
    }
  }
#pragma unroll
  for (int i = 0; i < 4; ++i) acc[i] += __shfl_xor(acc[i], 16);
#pragma unroll
  for (int i = 0; i < 4; ++i) acc[i] += __shfl_xor(acc[i], 32);
  float ov = g == 0 ? acc[0] : g == 1 ? acc[1] : g == 2 ? acc[2] : acc[3];
  int c = p * 4 + g;
  out[(size_t)gw * 64 + c] = ov + bias[c];
}

extern "C" void kernel_launch(void* const* d_in, const int* in_sizes, int n_in,
                              void* d_out, int out_size, void* d_ws, size_t ws_size,
                              hipStream_t stream) {
  const float* x      = (const float*)d_in[0];
  const void*  ei     = d_in[1];
  const float* W1     = (const float*)d_in[2];
  const float* a_src1 = (const float*)d_in[3];
  const float* a_dst1 = (const float*)d_in[4];
  const float* b1     = (const float*)d_in[5];
  const float* W2     = (const float*)d_in[6];
  const float* a_src2 = (const float*)d_in[7];
  const float* a_dst2 = (const float*)d_in[8];
  const float* b2     = (const float*)d_in[9];

  const int Fin = 128;
  const int N   = in_sizes[0] / Fin;  // 50000
  const int E   = in_sizes[1] / 2;    // 800000
  const int HC1 = in_sizes[2] / Fin;  // 256
  const int Etot = E + N;

  char* wp = (char*)d_ws;
  auto alloc = [&](size_t bytes) {
    void* p = (void*)wp;
    wp += (bytes + 255) & ~(size_t)255;
    return p;
  };
  int* counts    = (int*)alloc((size_t)N * 4);
  int* row_ptr   = (int*)alloc((size_t)(N + 1) * 4);
  int* cursor    = (int*)alloc((size_t)N * 4);
  int* partial   = (int*)alloc((size_t)N * 4);
  int* blocksums = (int*)alloc(4096);
  int* flag      = (int*)alloc(256);
  int* srcs      = (int*)alloc((size_t)Etot * 4);
  unsigned short* xh   = (unsigned short*)alloc((size_t)N * Fin * 2);
  unsigned short* xl   = (unsigned short*)alloc((size_t)N * Fin * 2);  // contiguous after xh
  unsigned short* W1th = (unsigned short*)alloc((size_t)HC1 * Fin * 2);
  unsigned short* W1tl = (unsigned short*)alloc((size_t)HC1 * Fin * 2);
  unsigned short* W2th = (unsigned short*)alloc((size_t)64 * HC1 * 2);
  unsigned short* W2tl = (unsigned short*)alloc((size_t)64 * HC1 * 2);
  unsigned short* h1b  = (unsigned short*)alloc((size_t)N * 256 * 2);
  float* as1 = (float*)alloc((size_t)N * 4 * 4);
  float* ad1 = (float*)alloc((size_t)N * 4 * 4);
  float* as2 = (float*)alloc((size_t)N * 4);
  float* ad2 = (float*)alloc((size_t)N * 4);
  // aliases (disjoint lifetimes):
  unsigned short* o1h = xh;   // xh+xl contiguous 25.6MB, dead after gemm1
  unsigned short* h2b = h1b;  // h1b dead after agg4

  const int SB = (N + 511) / 512;

  // ---- CSR build ----
  detect_i64_kernel<<<1, 64, 0, stream>>>((const int*)ei, flag);
  hipMemsetAsync(counts, 0, (size_t)N * 4, stream);
  hist_kernel<<<(Etot + 255) / 256, 256, 0, stream>>>(ei, flag, counts, E, N);
  scan1_kernel<<<SB, 512, 0, stream>>>(counts, partial, blocksums, N);
  scan2_kernel<<<1, 512, 0, stream>>>(blocksums, SB);
  scan3_kernel<<<(N + 255) / 256, 256, 0, stream>>>(partial, blocksums, row_ptr, cursor, N);
  scatter_kernel<<<(Etot + 255) / 256, 256, 0, stream>>>(ei, flag, cursor, srcs, E, N);

  // ---- prep ----
  int n4 = N * Fin / 4;
  split_kernel<<<(n4 + 255) / 256, 256, 0, stream>>>(x, xh, xl, n4);
  wprep_kernel<<<(Fin * HC1 + 255) / 256, 256, 0, stream>>>(W1, W1th, W1tl, Fin, HC1);
  wprep_kernel<<<(HC1 * 64 + 255) / 256, 256, 0, stream>>>(W2, W2th, W2tl, HC1, 64);

  // ---- layer 1: 3-seg GEMM (fp32-accurate) + fused alpha ----
  gemm_mfma<64, 256, 1, 4, 3><<<dim3(1, (N + 63) / 64), 256, 0, stream>>>(
      xh, xh, xl, W1th, W1tl, W1th, N, Fin, h1b, a_src1, a_dst1, as1, ad1);
  agg4<<<(N + 3) / 4, 256, 0, stream>>>(h1b, as1, ad1, row_ptr, srcs, b1, o1h, N);

  // ---- layer 2: 2-seg GEMM (bf16 A) + fused alpha ----
  gemm_mfma<256, 64, 0, 1, 2><<<dim3(1, (N + 255) / 256), 256, 0, stream>>>(
      o1h, o1h, o1h, W2th, W2tl, W2th, N, HC1, h2b, a_src2, a_dst2, as2, ad2);
  agg1<<<(N + 3) / 4, 256, 0, stream>>>(h2b, as2, ad2, row_ptr, srcs, b2, (float*)d_out, N);
}

// Round 5
// 287.356 us; speedup vs baseline: 1.7065x; 1.0328x over previous
//
#include <hip/hip_runtime.h>

#define LRELU(x) ((x) > 0.f ? (x) : 0.2f * (x))

typedef __attribute__((ext_vector_type(8))) short bf16x8;
typedef __attribute__((ext_vector_type(4))) float f32x4;

__device__ __forceinline__ unsigned short f2bf(float f) {
  unsigned int u = __float_as_uint(f);
  unsigned int r = (u + 0x7fffu + ((u >> 16) & 1u)) >> 16;  // RNE
  return (unsigned short)r;
}
__device__ __forceinline__ float bf2f(unsigned short u) {
  return __uint_as_float(((unsigned int)u) << 16);
}
__device__ __forceinline__ float bflo(unsigned int u) { return __uint_as_float(u << 16); }
__device__ __forceinline__ float bfhi(unsigned int u) { return __uint_as_float(u & 0xffff0000u); }

__device__ __forceinline__ void wait_vm5() { asm volatile("s_waitcnt vmcnt(5)" ::: "memory"); }
__device__ __forceinline__ void wait_vm0() { asm volatile("s_waitcnt vmcnt(0)" ::: "memory"); }
__device__ __forceinline__ void lgkm0()   { asm volatile("s_waitcnt lgkmcnt(0)" ::: "memory"); }

#define GLOAD_LDS16(g, l)                                                  \
  __builtin_amdgcn_global_load_lds(                                        \
      (const __attribute__((address_space(1))) void*)(g),                  \
      (__attribute__((address_space(3))) void*)(l), 16, 0, 0)

// ---- edge dtype detection ----
__global__ void detect_i64_kernel(const int* __restrict__ w, int* __restrict__ flag) {
  if (threadIdx.x == 0 && blockIdx.x == 0) {
    int all0 = 1;
    for (int j = 0; j < 128; j++)
      if (w[2 * j + 1] != 0) { all0 = 0; break; }
    *flag = all0;
  }
}
__device__ __forceinline__ int edge_at(const void* ei, long long idx, int is64) {
  if (is64) return (int)((const long long*)ei)[idx];
  return ((const int*)ei)[idx];
}

// ---- CSR build ----
__global__ void hist_kernel(const void* __restrict__ ei, const int* __restrict__ flag,
                            int* __restrict__ counts, int E, int N) {
  int i = blockIdx.x * blockDim.x + threadIdx.x;
  int tot = E + N;
  if (i >= tot) return;
  int f = *flag;
  int d = (i < E) ? edge_at(ei, (long long)E + i, f) : (i - E);
  atomicAdd(&counts[d], 1);
}

__global__ __launch_bounds__(512) void scan1_kernel(const int* __restrict__ counts,
                                                    int* __restrict__ partial,
                                                    int* __restrict__ blocksums, int N) {
  __shared__ int sm[1024];
  int t = threadIdx.x;
  int i = blockIdx.x * 512 + t;
  int v = (i < N) ? counts[i] : 0;
  int* cur = sm; int* nxt = sm + 512;
  cur[t] = v;
  __syncthreads();
  for (int off = 1; off < 512; off <<= 1) {
    int x = cur[t];
    if (t >= off) x += cur[t - off];
    nxt[t] = x;
    __syncthreads();
    int* tmp = cur; cur = nxt; nxt = tmp;
  }
  if (i < N) partial[i] = cur[t];
  if (t == 511) blocksums[blockIdx.x] = cur[511];
}

__global__ __launch_bounds__(512) void scan2_kernel(int* __restrict__ bs, int B) {
  __shared__ int sm[1024];
  int t = threadIdx.x;
  int v = (t < B) ? bs[t] : 0;
  int* cur = sm; int* nxt = sm + 512;
  cur[t] = v;
  __syncthreads();
  for (int off = 1; off < 512; off <<= 1) {
    int x = cur[t];
    if (t >= off) x += cur[t - off];
    nxt[t] = x;
    __syncthreads();
    int* tmp = cur; cur = nxt; nxt = tmp;
  }
  if (t < B) bs[t] = cur[t] - v;
}

__global__ void scan3_kernel(const int* __restrict__ partial, const int* __restrict__ bs,
                             int* __restrict__ row_ptr, int* __restrict__ cursor, int N) {
  int i = blockIdx.x * blockDim.x + threadIdx.x;
  if (i == 0) { row_ptr[0] = 0; cursor[0] = 0; }
  if (i < N) {
    int v = partial[i] + bs[i >> 9];
    row_ptr[i + 1] = v;
    if (i + 1 < N) cursor[i + 1] = v;
  }
}

__global__ void scatter_kernel(const void* __restrict__ ei, const int* __restrict__ flag,
                               int* __restrict__ cursor, int* __restrict__ srcs, int E, int N) {
  int i = blockIdx.x * blockDim.x + threadIdx.x;
  int tot = E + N;
  if (i >= tot) return;
  int f = *flag;
  int s, d;
  if (i < E) {
    s = edge_at(ei, i, f);
    d = edge_at(ei, (long long)E + i, f);
  } else {
    s = i - E; d = s;
  }
  int pos = atomicAdd(&cursor[d], 1);
  srcs[pos] = s;
}

// ---- prep: fp32 -> bf16 (hi only) ----
__global__ __launch_bounds__(256) void tobf16_kernel(const float* __restrict__ x,
                                                     unsigned short* __restrict__ xh, int n4) {
  int i = blockIdx.x * 256 + threadIdx.x;
  if (i >= n4) return;
  float4 v = ((const float4*)x)[i];
  ushort4 h;
  h.x = f2bf(v.x); h.y = f2bf(v.y); h.z = f2bf(v.z); h.w = f2bf(v.w);
  ((ushort4*)xh)[i] = h;
}

// ---- prep: transpose + split W [K][Nc] -> Wt_h/Wt_l [Nc][K] ----
__global__ __launch_bounds__(256) void wprep_kernel(const float* __restrict__ W,
                                                    unsigned short* __restrict__ Wth,
                                                    unsigned short* __restrict__ Wtl,
                                                    int K, int Nc) {
  int idx = blockIdx.x * 256 + threadIdx.x;
  if (idx >= K * Nc) return;
  int n = idx / K, k = idx - n * K;
  float v = W[(size_t)k * Nc + n];
  unsigned short h = f2bf(v);
  Wth[idx] = h;
  Wtl[idx] = f2bf(v - bf2f(h));
}

// ---- MFMA GEMM, 2 segments (A@B0 + A@B1), global_load_lds + dbuf + counted vmcnt ----
// B stored transposed [col][k]. Fused alpha epilogue.
template <int BROWS, int BCOLS, int WALONG_N, int H>
__global__ __launch_bounds__(256) void gemm_mfma(
    const unsigned short* __restrict__ A0, const unsigned short* __restrict__ B0,
    const unsigned short* __restrict__ B1, int M, int Ka,
    unsigned short* __restrict__ Cb, const float* __restrict__ asrc,
    const float* __restrict__ adst, float* __restrict__ as, float* __restrict__ ad) {
  __shared__ __align__(16) unsigned short Asm[2][4][BROWS][8];
  __shared__ __align__(16) unsigned short Bsm[2][4][BCOLS][8];
  int tid = threadIdx.x;
  int w = tid >> 6, l = tid & 63;
  int l16 = l & 15, lg = l >> 4;
  int rowbase = blockIdx.y * BROWS;
  int wrow = WALONG_N ? 0 : w * 64;
  int wcol = WALONG_N ? w * 64 : 0;
  const int KS = Ka / 32;        // k-steps per segment
  const int NST = 2 * KS;        // total pipeline steps
  const int CH_A = BROWS * 4 / 256;
  const int CH_B = BCOLS * 4 / 256;

  auto stage = [&](int buf, int s) {
    int seg = s / KS;
    int kk = (s - seg * KS) * 32;
    const unsigned short* Bp = seg ? B1 : B0;
#pragma unroll
    for (int q = 0; q < CH_A; ++q) {
      int i = q * 256 + tid;
      int p = i / BROWS, r = i % BROWS;
      int gr = rowbase + r;
      if (gr >= M) gr = M - 1;
      const unsigned short* src = A0 + (size_t)gr * Ka + kk + p * 8;
      unsigned short* dst = &Asm[buf][0][0][0] + ((size_t)q * 256 + (tid & ~63)) * 8;
      GLOAD_LDS16(src, dst);
    }
#pragma unroll
    for (int q = 0; q < CH_B; ++q) {
      int i = q * 256 + tid;
      int p = i / BCOLS, r = i % BCOLS;
      const unsigned short* src = Bp + (size_t)r * Ka + kk + p * 8;
      unsigned short* dst = &Bsm[buf][0][0][0] + ((size_t)q * 256 + (tid & ~63)) * 8;
      GLOAD_LDS16(src, dst);
    }
  };

  f32x4 acc[4][4] = {};
  stage(0, 0);
  int buf = 0;
  for (int s = 0; s < NST; ++s) {
    if (s + 1 < NST) { stage(buf ^ 1, s + 1); wait_vm5(); }
    else             { wait_vm0(); }
    __builtin_amdgcn_s_barrier();
    bf16x8 af[4], bfr[4];
#pragma unroll
    for (int m = 0; m < 4; ++m) af[m] = *(const bf16x8*)&Asm[buf][lg][wrow + m * 16 + l16][0];
#pragma unroll
    for (int n = 0; n < 4; ++n) bfr[n] = *(const bf16x8*)&Bsm[buf][lg][wcol + n * 16 + l16][0];
#pragma unroll
    for (int m = 0; m < 4; ++m)
#pragma unroll
      for (int n = 0; n < 4; ++n)
        acc[m][n] = __builtin_amdgcn_mfma_f32_16x16x32_bf16(af[m], bfr[n], acc[m][n], 0, 0, 0);
    __builtin_amdgcn_s_barrier();
    buf ^= 1;
  }
  // epilogue: bf16 store
#pragma unroll
  for (int m = 0; m < 4; ++m) {
    int r = rowbase + wrow + m * 16 + lg * 4;
#pragma unroll
    for (int n = 0; n < 4; ++n) {
      int c = wcol + n * 16 + l16;
#pragma unroll
      for (int j = 0; j < 4; ++j) {
        if (r + j < M) Cb[(size_t)(r + j) * BCOLS + c] = f2bf(acc[m][n][j]);
      }
    }
  }
  // fused alpha epilogue
  float asv[4], adv_[4];
#pragma unroll
  for (int n = 0; n < 4; ++n) {
    int c = wcol + n * 16 + l16;
    asv[n] = asrc[c];
    adv_[n] = adst[c];
  }
  int head = WALONG_N ? w : 0;
#pragma unroll
  for (int m = 0; m < 4; ++m) {
#pragma unroll
    for (int j = 0; j < 4; ++j) {
      float ps = 0.f, pd = 0.f;
#pragma unroll
      for (int n = 0; n < 4; ++n) {
        ps = fmaf(acc[m][n][j], asv[n], ps);
        pd = fmaf(acc[m][n][j], adv_[n], pd);
      }
#pragma unroll
      for (int o = 1; o < 16; o <<= 1) { ps += __shfl_xor(ps, o); pd += __shfl_xor(pd, o); }
      int r = rowbase + wrow + m * 16 + lg * 4 + j;
      if (l16 == 0 && r < M) {
        as[(size_t)r * H + head] = ps;
        ad[(size_t)r * H + head] = pd;
      }
    }
  }
}

// ---- layer-1 aggregation: wave per node; lane=(g,p): edge-offset g, 16 channels p ----
__global__ __launch_bounds__(256) void agg4(const unsigned short* __restrict__ hb,
                                            const float* __restrict__ as,
                                            const float* __restrict__ ad,
                                            const int* __restrict__ row_ptr,
                                            const int* __restrict__ srcs,
                                            const float* __restrict__ bias,
                                            unsigned short* __restrict__ oh, int N) {
  __shared__ float els[4][128][4];
  int tid = threadIdx.x;
  int w = tid >> 6, l = tid & 63;
  int gw = (blockIdx.x << 2) + w;
  if (gw >= N) gw = N - 1;
  int g = l >> 4, p = l & 15;
  int beg = row_ptr[gw], end = row_ptr[gw + 1];
  float4 adv = *(const float4*)(ad + (size_t)gw * 4);
  // phase 1: per-lane max over strided edges; stash e in (wave-private) LDS
  float m0 = -1e30f, m1 = -1e30f, m2 = -1e30f, m3 = -1e30f;
  for (int j = beg + l; j < end; j += 64) {
    int sn = srcs[j];
    float4 a = *(const float4*)(as + (size_t)sn * 4);
    float e0 = LRELU(a.x + adv.x), e1 = LRELU(a.y + adv.y);
    float e2 = LRELU(a.z + adv.z), e3 = LRELU(a.w + adv.w);
    int slot = j - beg;
    if (slot < 128) {
      els[w][slot][0] = e0; els[w][slot][1] = e1;
      els[w][slot][2] = e2; els[w][slot][3] = e3;
    }
    m0 = fmaxf(m0, e0); m1 = fmaxf(m1, e1);
    m2 = fmaxf(m2, e2); m3 = fmaxf(m3, e3);
  }
#pragma unroll
  for (int o = 32; o; o >>= 1) {
    m0 = fmaxf(m0, __shfl_xor(m0, o));
    m1 = fmaxf(m1, __shfl_xor(m1, o));
    m2 = fmaxf(m2, __shfl_xor(m2, o));
    m3 = fmaxf(m3, __shfl_xor(m3, o));
  }
  lgkm0();  // stash visible within wave (no cross-wave barrier needed)
  // phase 2: sum of exp over own slots
  float s0 = 0.f, s1 = 0.f, s2 = 0.f, s3 = 0.f;
  for (int j = beg + l; j < end; j += 64) {
    int slot = j - beg;
    float e0, e1, e2, e3;
    if (slot < 128) {
      e0 = els[w][slot][0]; e1 = els[w][slot][1];
      e2 = els[w][slot][2]; e3 = els[w][slot][3];
    } else {
      int sn = srcs[j];
      float4 a = *(const float4*)(as + (size_t)sn * 4);
      e0 = LRELU(a.x + adv.x); e1 = LRELU(a.y + adv.y);
      e2 = LRELU(a.z + adv.z); e3 = LRELU(a.w + adv.w);
    }
    s0 += __expf(e0 - m0); s1 += __expf(e1 - m1);
    s2 += __expf(e2 - m2); s3 += __expf(e3 - m3);
  }
#pragma unroll
  for (int o = 32; o; o >>= 1) {
    s0 += __shfl_xor(s0, o); s1 += __shfl_xor(s1, o);
    s2 += __shfl_xor(s2, o); s3 += __shfl_xor(s3, o);
  }
  float i0 = 1.f / (s0 + 1e-16f), i1 = 1.f / (s1 + 1e-16f);
  float i2 = 1.f / (s2 + 1e-16f), i3 = 1.f / (s3 + 1e-16f);
  // phase 3: lane handles edge j0+g, channels p*16..p*16+15 (head=p>>2)
  int head = p >> 2;
  float Mh   = head == 0 ? m0 : head == 1 ? m1 : head == 2 ? m2 : m3;
  float Ih   = head == 0 ? i0 : head == 1 ? i1 : head == 2 ? i2 : i3;
  float advh = head == 0 ? adv.x : head == 1 ? adv.y : head == 2 ? adv.z : adv.w;
  float acc[16] = {};
  for (int j0 = beg; j0 < end; j0 += 4) {
    int j = j0 + g;
    if (j < end) {
      int sn = srcs[j];
      int slot = j - beg;
      float e;
      if (slot < 128) {
        e = els[w][slot][head];
      } else {
        float4 a = *(const float4*)(as + (size_t)sn * 4);
        float ah = head == 0 ? a.x : head == 1 ? a.y : head == 2 ? a.z : a.w;
        e = LRELU(ah + advh);
      }
      float al = __expf(e - Mh) * Ih;
      const unsigned short* hp = hb + (size_t)sn * 256 + p * 16;
      uint4 v0 = *(const uint4*)(hp);
      uint4 v1 = *(const uint4*)(hp + 8);
      acc[0]  = fmaf(al, bflo(v0.x), acc[0]);  acc[1]  = fmaf(al, bfhi(v0.x), acc[1]);
      acc[2]  = fmaf(al, bflo(v0.y), acc[2]);  acc[3]  = fmaf(al, bfhi(v0.y), acc[3]);
      acc[4]  = fmaf(al, bflo(v0.z), acc[4]);  acc[5]  = fmaf(al, bfhi(v0.z), acc[5]);
      acc[6]  = fmaf(al, bflo(v0.w), acc[6]);  acc[7]  = fmaf(al, bfhi(v0.w), acc[7]);
      acc[8]  = fmaf(al, bflo(v1.x), acc[8]);  acc[9]  = fmaf(al, bfhi(v1.x), acc[9]);
      acc[10] = fmaf(al, bflo(v1.y), acc[10]); acc[11] = fmaf(al, bfhi(v1.y), acc[11]);
      acc[12] = fmaf(al, bflo(v1.z), acc[12]); acc[13] = fmaf(al, bfhi(v1.z), acc[13]);
      acc[14] = fmaf(al, bflo(v1.w), acc[14]); acc[15] = fmaf(al, bfhi(v1.w), acc[15]);
    }
  }
#pragma unroll
  for (int i = 0; i < 16; ++i) acc[i] += __shfl_xor(acc[i], 16);
#pragma unroll
  for (int i = 0; i < 16; ++i) acc[i] += __shfl_xor(acc[i], 32);
  float o0 = g == 0 ? acc[0] : g == 1 ? acc[4]  : g == 2 ? acc[8]  : acc[12];
  float o1 = g == 0 ? acc[1] : g == 1 ? acc[5]  : g == 2 ? acc[9]  : acc[13];
  float o2 = g == 0 ? acc[2] : g == 1 ? acc[6]  : g == 2 ? acc[10] : acc[14];
  float o3 = g == 0 ? acc[3] : g == 1 ? acc[7]  : g == 2 ? acc[11] : acc[15];
  int c = p * 16 + g * 4;
  ushort4 ov;
  ov.x = f2bf(fmaxf(o0 + bias[c + 0], 0.f));
  ov.y = f2bf(fmaxf(o1 + bias[c + 1], 0.f));
  ov.z = f2bf(fmaxf(o2 + bias[c + 2], 0.f));
  ov.w = f2bf(fmaxf(o3 + bias[c + 3], 0.f));
  *(ushort4*)(oh + (size_t)gw * 256 + c) = ov;
}

// ---- layer-2 aggregation: wave per node; lane=(g,p): edge g, 4 channels p ----
__global__ __launch_bounds__(256) void agg1(const unsigned short* __restrict__ hb,
                                            const float* __restrict__ as,
                                            const float* __restrict__ ad,
                                            const int* __restrict__ row_ptr,
                                            const int* __restrict__ srcs,
                                            const float* __restrict__ bias,
                                            float* __restrict__ out, int N) {
  __shared__ float els[4][128];
  int tid = threadIdx.x;
  int w = tid >> 6, l = tid & 63;
  int gw = (blockIdx.x << 2) + w;
  if (gw >= N) gw = N - 1;
  int g = l >> 4, p = l & 15;
  int beg = row_ptr[gw], end = row_ptr[gw + 1];
  float adn = ad[gw];
  float m = -1e30f;
  for (int j = beg + l; j < end; j += 64) {
    float e = LRELU(as[srcs[j]] + adn);
    int slot = j - beg;
    if (slot < 128) els[w][slot] = e;
    m = fmaxf(m, e);
  }
#pragma unroll
  for (int o = 32; o; o >>= 1) m = fmaxf(m, __shfl_xor(m, o));
  lgkm0();
  float s = 0.f;
  for (int j = beg + l; j < end; j += 64) {
    int slot = j - beg;
    float e = (slot < 128) ? els[w][slot] : LRELU(as[srcs[j]] + adn);
    s += __expf(e - m);
  }
#pragma unroll
  for (int o = 32; o; o >>= 1) s += __shfl_xor(s, o);
  float inv = 1.f / (s + 1e-16f);
  float acc[4] = {};
  for (int j0 = beg; j0 < end; j0 += 4) {
    int j = j0 + g;
    if (j < end) {
      int sn = srcs[j];
      int slot = j - beg;
      float e = (slot < 128) ? els[w][slot] : LRELU(as[sn] + adn);
      float al = __expf(e - m) * inv;
      ushort4 hv = *(const ushort4*)(hb + (size_t)sn * 64 + p * 4);
      acc[0] = fmaf(al, bf2f(hv.x), acc[0]);
      acc[1] = fmaf(al, bf2f(hv.y), acc[1]);
      acc[2] = fmaf(al, bf2f(hv.z), acc[2]);
      acc[3] = fmaf(al, bf2f(hv.w), acc[3]);
    }
  }
#pragma unroll
  for (int i = 0; i < 4; ++i) acc[i] += __shfl_xor(acc[i], 16);
#pragma unroll
  for (int i = 0; i < 4; ++i) acc[i] += __shfl_xor(acc[i], 32);
  float ov = g == 0 ? acc[0] : g == 1 ? acc[1] : g == 2 ? acc[2] : acc[3];
  int c = p * 4 + g;
  out[(size_t)gw * 64 + c] = ov + bias[c];
}

extern "C" void kernel_launch(void* const* d_in, const int* in_sizes, int n_in,
                              void* d_out, int out_size, void* d_ws, size_t ws_size,
                              hipStream_t stream) {
  const float* x      = (const float*)d_in[0];
  const void*  ei     = d_in[1];
  const float* W1     = (const float*)d_in[2];
  const float* a_src1 = (const float*)d_in[3];
  const float* a_dst1 = (const float*)d_in[4];
  const float* b1     = (const float*)d_in[5];
  const float* W2     = (const float*)d_in[6];
  const float* a_src2 = (const float*)d_in[7];
  const float* a_dst2 = (const float*)d_in[8];
  const float* b2     = (const float*)d_in[9];

  const int Fin = 128;
  const int N   = in_sizes[0] / Fin;  // 50000
  const int E   = in_sizes[1] / 2;    // 800000
  const int HC1 = in_sizes[2] / Fin;  // 256
  const int Etot = E + N;

  char* wp = (char*)d_ws;
  auto alloc = [&](size_t bytes) {
    void* p = (void*)wp;
    wp += (bytes + 255) & ~(size_t)255;
    return p;
  };
  int* counts    = (int*)alloc((size_t)N * 4);
  int* row_ptr   = (int*)alloc((size_t)(N + 1) * 4);
  int* cursor    = (int*)alloc((size_t)N * 4);
  int* partial   = (int*)alloc((size_t)N * 4);
  int* blocksums = (int*)alloc(4096);
  int* flag      = (int*)alloc(256);
  int* srcs      = (int*)alloc((size_t)Etot * 4);
  unsigned short* xh   = (unsigned short*)alloc((size_t)N * Fin * 2);   // 12.8MB
  unsigned short* xpad = (unsigned short*)alloc((size_t)N * Fin * 2);   // pad region (o1h tail)
  unsigned short* W1th = (unsigned short*)alloc((size_t)HC1 * Fin * 2);
  unsigned short* W1tl = (unsigned short*)alloc((size_t)HC1 * Fin * 2);
  unsigned short* W2th = (unsigned short*)alloc((size_t)64 * HC1 * 2);
  unsigned short* W2tl = (unsigned short*)alloc((size_t)64 * HC1 * 2);
  unsigned short* h1b  = (unsigned short*)alloc((size_t)N * 256 * 2);   // 25.6MB
  float* as1 = (float*)alloc((size_t)N * 4 * 4);
  float* ad1 = (float*)alloc((size_t)N * 4 * 4);
  float* as2 = (float*)alloc((size_t)N * 4);
  float* ad2 = (float*)alloc((size_t)N * 4);
  (void)xpad;
  // aliases (disjoint lifetimes):
  unsigned short* o1h = xh;   // xh+xpad contiguous 25.6MB; xh dead after gemm1
  unsigned short* h2b = h1b;  // h1b dead after agg4

  const int SB = (N + 511) / 512;

  // ---- CSR build ----
  detect_i64_kernel<<<1, 64, 0, stream>>>((const int*)ei, flag);
  hipMemsetAsync(counts, 0, (size_t)N * 4, stream);
  hist_kernel<<<(Etot + 255) / 256, 256, 0, stream>>>(ei, flag, counts, E, N);
  scan1_kernel<<<SB, 512, 0, stream>>>(counts, partial, blocksums, N);
  scan2_kernel<<<1, 512, 0, stream>>>(blocksums, SB);
  scan3_kernel<<<(N + 255) / 256, 256, 0, stream>>>(partial, blocksums, row_ptr, cursor, N);
  scatter_kernel<<<(Etot + 255) / 256, 256, 0, stream>>>(ei, flag, cursor, srcs, E, N);

  // ---- prep ----
  int n4 = N * Fin / 4;
  tobf16_kernel<<<(n4 + 255) / 256, 256, 0, stream>>>(x, xh, n4);
  wprep_kernel<<<(Fin * HC1 + 255) / 256, 256, 0, stream>>>(W1, W1th, W1tl, Fin, HC1);
  wprep_kernel<<<(HC1 * 64 + 255) / 256, 256, 0, stream>>>(W2, W2th, W2tl, HC1, 64);

  // ---- layer 1: 2-seg GEMM (xh@Wh + xh@Wl) + fused alpha ----
  gemm_mfma<64, 256, 1, 4><<<dim3(1, (N + 63) / 64), 256, 0, stream>>>(
      xh, W1th, W1tl, N, Fin, h1b, a_src1, a_dst1, as1, ad1);
  agg4<<<(N + 3) / 4, 256, 0, stream>>>(h1b, as1, ad1, row_ptr, srcs, b1, o1h, N);

  // ---- layer 2: 2-seg GEMM (o1h@Wh + o1h@Wl) + fused alpha ----
  gemm_mfma<256, 64, 0, 1><<<dim3(1, (N + 255) / 256), 256, 0, stream>>>(
      o1h, W2th, W2tl, N, HC1, h2b, a_src2, a_dst2, as2, ad2);
  agg1<<<(N + 3) / 4, 256, 0, stream>>>(h2b, as2, ad2, row_ptr, srcs, b2, (float*)d_out, N);
}